// Round 5
// baseline (73.786 us; speedup 1.0000x reference)
//
#include <hip/hip_runtime.h>
#include <math.h>

#define BATCH 16
#define CHN   16
#define IMH   96
#define IMW   320
#define HW    (IMH*IMW)          /* 30720 */
#define NBLK  (HW/256)           /* 120 blocks per batch */
#define NSLOT (NBLK*4)           /* 480 per-wave partial slots per batch */
#define NPART 27                 /* 21 (sym H) + 6 (b) */
#define ROWB  (IMW*16)           /* fp8 row stride in bytes */

typedef __attribute__((ext_vector_type(2))) float f32x2;

__device__ __forceinline__ int comp4(int4 v, int k) {
    switch (k) { case 0: return v.x; case 1: return v.y; case 2: return v.z; default: return v.w; }
}

// wave64 sum via DPP (row_shr 1/2/4/8 + row_bcast 15/31); result valid in lane 63.
__device__ __forceinline__ float dpp_wave_sum(float x) {
    union fi { float f; int i; };
    fi v; v.f = x;
#define DPPSTEP(CTRL, RM) { fi t; t.i = __builtin_amdgcn_update_dpp(0, v.i, CTRL, RM, 0xf, true); v.f += t.f; }
    DPPSTEP(0x111, 0xf)   /* row_shr:1 */
    DPPSTEP(0x112, 0xf)   /* row_shr:2 */
    DPPSTEP(0x114, 0xf)   /* row_shr:4 */
    DPPSTEP(0x118, 0xf)   /* row_shr:8  -> lane 15+16r = row sum */
    DPPSTEP(0x142, 0xa)   /* row_bcast:15 -> lane31=r0+r1, lane63=r2+r3 */
    DPPSTEP(0x143, 0xc)   /* row_bcast:31 -> lane63 = total */
#undef DPPSTEP
    return v.f;
}

// ---------------- kernel 0: transpose+quantize tgt_feat (B,C,H,W) fp32 -> (B,H,W,16) fp8 e4m3 ----------------
__global__ __launch_bounds__(256) void transpose_tgt(const float* __restrict__ in,
                                                     char* __restrict__ out) {
    const int b = blockIdx.y;
    const int p = blockIdx.x * 256 + threadIdx.x;
    const float* ip = in + (size_t)b * CHN * HW + p;
    float f[16];
#pragma unroll
    for (int c = 0; c < 16; ++c) f[c] = ip[c * HW];
    int4 pk;
    int* pw = &pk.x;
#pragma unroll
    for (int k = 0; k < 4; ++k) {
        int dw = __builtin_amdgcn_cvt_pk_fp8_f32(f[4 * k + 0], f[4 * k + 1], 0, false);
        dw     = __builtin_amdgcn_cvt_pk_fp8_f32(f[4 * k + 2], f[4 * k + 3], dw, true);
        pw[k] = dw;
    }
    *(int4*)(out + ((size_t)b * HW + p) * 16) = pk;
}

// ---------------- kernel 1: per-point moments + per-wave partial H/b (fp8 gathers) ----------------
__global__ __launch_bounds__(256, 4) void gn_accum(
    const float* __restrict__ p2,        // (B,2,5,1,H,W)
    const float* __restrict__ P2,        // (B,3,HW)
    const float* __restrict__ calibK,    // (B,3,3)
    const float* __restrict__ weight,    // (B,1,H,W)
    const float* __restrict__ src_feat,  // (B,C,H,W)
    const float* __restrict__ src_w,     // (B,1,H,W)
    const float* __restrict__ tgt_w,     // (B,1,H,W)
    const char* __restrict__ tf8,        // (B,H,W,16) fp8
    float* __restrict__ partials)        // (B, NSLOT, NPART)
{
    __shared__ float xs_l[1280];
    __shared__ float ys_l[1280];

    // XCD pinning: XCD k serves batches {k, k+8} -> 2 fp8 maps (1.6 MB) per L2
    const int n   = blockIdx.x;
    const int b   = n & 15;
    const int blk = n >> 4;
    const int t   = threadIdx.x;
    const int p   = blk * 256 + t;

    // ---- cooperative coalesced stage of the block's 1280 grid coords ----
    // Block covers G in [Gblk0, Gblk0+1280): contiguous q-runs in p2.
    const unsigned Gblk0 = ((unsigned)b * HW + (unsigned)(blk * 256)) * 5u;
#pragma unroll
    for (int j = 0; j < 5; ++j) {
        const unsigned idx  = (unsigned)(j * 256 + t);
        const unsigned G    = Gblk0 + idx;
        const unsigned sBig = G / (unsigned)(BATCH * HW);
        const unsigned r    = G - sBig * (unsigned)(BATCH * HW);
        const unsigned bb   = r / (unsigned)HW;
        const unsigned q    = r - bb * (unsigned)HW;
        const float* pb = p2 + (size_t)bb * (10 * HW) + (size_t)sBig * HW + q;
        xs_l[idx] = pb[0];
        ys_l[idx] = pb[5 * HW];
    }
    __syncthreads();

    // ---- per-point sample geometry from LDS ----
    int   off[5];
    float wxs[5], wys[5];
    int   pix00 = 0;
#pragma unroll
    for (int s = 0; s < 5; ++s) {
        const float xp = xs_l[5 * t + s];
        const float yp = ys_l[5 * t + s];
        float gx = 2.0f * (xp + 0.5f) / (float)IMW - 1.0f;
        float gy = 2.0f * (yp + 0.5f) / (float)IMH - 1.0f;
        float x  = (gx + 1.0f) * ((float)IMW * 0.5f) - 0.5f;
        float y  = (gy + 1.0f) * ((float)IMH * 0.5f) - 0.5f;
        float x0 = floorf(x), y0 = floorf(y);
        wxs[s] = x - x0;
        wys[s] = y - y0;
        int xi = (int)x0, yi = (int)y0;
        xi = min(max(xi, 0), IMW - 2);
        yi = min(max(yi, 0), IMH - 2);
        off[s] = ((b * IMH + yi) * IMW + xi) * 16;
        if (s == 0) pix00 = b * HW + yi * IMW + xi;
    }

    // ---- issue all loads up front (20 fp8 gathers + 4 tgt_w + 16 src_feat + misc) ----
    int4 LA[5], LB[5], LC[5], LD[5];
#pragma unroll
    for (int s = 0; s < 5; ++s) {
        const char* bp = tf8 + off[s];
        LA[s] = *(const int4*)(bp);
        LB[s] = *(const int4*)(bp + 16);
        LC[s] = *(const int4*)(bp + ROWB);
        LD[s] = *(const int4*)(bp + ROWB + 16);
    }
    const float* twb = tgt_w + pix00;
    const float v00 = twb[0], v01 = twb[1], v10 = twb[IMW], v11 = twb[IMW + 1];

    float srcv[16];
    const float* srcb = src_feat + (size_t)b * CHN * HW + p;
#pragma unroll
    for (int c = 0; c < 16; ++c) srcv[c] = srcb[c * HW];

    const float* P2b = P2 + (size_t)b * 3 * HW;
    const float X = P2b[p], Y = P2b[HW + p], Z = P2b[2 * HW + p];
    const float wP  = weight[(size_t)b * HW + p];
    const float swP = src_w[(size_t)b * HW + p];

    // ---- pixel Jacobian rows ----
    const float fx = calibK[b * 9 + 0];
    const float fy = calibK[b * 9 + 4];
    const float fxZ = fx / Z, fyZ = fy / Z;
    const float fxXZ2 = fxZ * X / Z;
    const float fyYZ2 = fyZ * Y / Z;
    float r0[6] = { fxZ, 0.0f, -fxXZ2, -fxXZ2 * Y, fx + fxXZ2 * X, -fxZ * Y };
    float r1[6] = { 0.0f, fyZ, -fyYZ2, -fy - fyYZ2 * Y, fyYZ2 * X, fyZ * X };

    // ---- weights ----
    float wtw;
    {
        float wx = wxs[0], wy = wys[0];
        wtw = v00 * (1.0f - wx) * (1.0f - wy) + v01 * wx * (1.0f - wy)
            + v10 * (1.0f - wx) * wy          + v11 * wx * wy;
    }
    const float w = swP * wtw * wP;

    float w00[5], w01[5], w10[5], w11[5];
#pragma unroll
    for (int s = 0; s < 5; ++s) {
        float wx = wxs[s], wy = wys[s];
        w00[s] = (1.0f - wx) * (1.0f - wy);
        w01[s] = wx * (1.0f - wy);
        w10[s] = (1.0f - wx) * wy;
        w11[s] = wx * wy;
    }

    // ---- channel-dword passes: decode fp8, bilinear-mix, accumulate moments ----
    float Sxx = 0.0f, Sxy = 0.0f, Syy = 0.0f, Tx = 0.0f, Ty = 0.0f;
#pragma unroll
    for (int k = 0; k < 4; ++k) {
        float fs[5][4];
#pragma unroll
        for (int s = 0; s < 5; ++s) {
            f32x2 alo = __builtin_amdgcn_cvt_pk_f32_fp8(comp4(LA[s], k), false);
            f32x2 ahi = __builtin_amdgcn_cvt_pk_f32_fp8(comp4(LA[s], k), true);
            f32x2 blo = __builtin_amdgcn_cvt_pk_f32_fp8(comp4(LB[s], k), false);
            f32x2 bhi = __builtin_amdgcn_cvt_pk_f32_fp8(comp4(LB[s], k), true);
            f32x2 clo = __builtin_amdgcn_cvt_pk_f32_fp8(comp4(LC[s], k), false);
            f32x2 chi = __builtin_amdgcn_cvt_pk_f32_fp8(comp4(LC[s], k), true);
            f32x2 dlo = __builtin_amdgcn_cvt_pk_f32_fp8(comp4(LD[s], k), false);
            f32x2 dhi = __builtin_amdgcn_cvt_pk_f32_fp8(comp4(LD[s], k), true);
            float a[4]  = { alo[0], alo[1], ahi[0], ahi[1] };
            float bq[4] = { blo[0], blo[1], bhi[0], bhi[1] };
            float c[4]  = { clo[0], clo[1], chi[0], chi[1] };
            float d[4]  = { dlo[0], dlo[1], dhi[0], dhi[1] };
#pragma unroll
            for (int j = 0; j < 4; ++j)
                fs[s][j] = a[j] * w00[s] + bq[j] * w01[s] + c[j] * w10[s] + d[j] * w11[s];
        }
#pragma unroll
        for (int j = 0; j < 4; ++j) {
            float sv  = srcv[4 * k + j];
            float res = sv - fs[0][j];
            float gx  = (fs[1][j] - fs[2][j]) * 0.5f;
            float gy  = (fs[3][j] - fs[4][j]) * 0.5f;
            Sxx += gx * gx; Sxy += gx * gy; Syy += gy * gy;
            Tx  += res * gx; Ty  += res * gy;
        }
    }

    const float Pm = w * Sxx, Qm = w * Sxy, Rm = w * Syy;
    const float tx = w * Tx,  ty = w * Ty;

    // ---- 27 per-wave sums via DPP; lane 63 writes this wave's slot ----
    const int wv   = t >> 6;
    const int lane = t & 63;
    float* pout = partials + ((size_t)b * NSLOT + (size_t)(blk * 4 + wv)) * NPART;

    int idx = 0;
#pragma unroll
    for (int k = 0; k < 6; ++k) {
#pragma unroll
        for (int l = 0; l < 6; ++l) {
            if (l < k) continue;
            float v = Pm * r0[k] * r0[l]
                    + Qm * (r0[k] * r1[l] + r1[k] * r0[l])
                    + Rm * r1[k] * r1[l];
            v = dpp_wave_sum(v);
            if (lane == 63) pout[idx] = v;
            ++idx;
        }
    }
#pragma unroll
    for (int k = 0; k < 6; ++k) {
        float v = tx * r0[k] + ty * r1[k];
        v = dpp_wave_sum(v);
        if (lane == 63) pout[21 + k] = v;
    }
}

// ---------------- kernel 2: double reduce + solve + se3_exp + compose ----------------
__global__ __launch_bounds__(256) void gn_solve(
    const float* __restrict__ partials,
    const float* __restrict__ poses,
    float* __restrict__ out)
{
    const int b = blockIdx.x;
    const int t = threadIdx.x;
    __shared__ double dsum[8][NPART];
    __shared__ double sums[NPART];

    if (t < 216) {
        const int col = t % NPART;
        const int g   = t / NPART;     // 0..7
        double s = 0.0;
        for (int j = g; j < NSLOT; j += 8)
            s += (double)partials[((size_t)b * NSLOT + j) * NPART + col];
        dsum[g][col] = s;
    }
    __syncthreads();
    if (t < NPART) {
        double s = 0.0;
#pragma unroll
        for (int g = 0; g < 8; ++g) s += dsum[g][t];
        sums[t] = s;
    }
    __syncthreads();
    if (t != 0) return;

    double A[6][7];
    {
        int idx = 0;
        for (int k = 0; k < 6; ++k)
            for (int l = k; l < 6; ++l) {
                A[k][l] = sums[idx];
                A[l][k] = sums[idx];
                ++idx;
            }
        for (int k = 0; k < 6; ++k) A[k][6] = sums[21 + k];
    }
    for (int col = 0; col < 6; ++col) {
        int piv = col; double mx = fabs(A[col][col]);
        for (int rr = col + 1; rr < 6; ++rr) {
            double v = fabs(A[rr][col]);
            if (v > mx) { mx = v; piv = rr; }
        }
        if (piv != col)
            for (int j = col; j < 7; ++j) { double tmp = A[col][j]; A[col][j] = A[piv][j]; A[piv][j] = tmp; }
        double d = A[col][col];
        for (int rr = col + 1; rr < 6; ++rr) {
            double f = A[rr][col] / d;
            for (int j = col; j < 7; ++j) A[rr][j] -= f * A[col][j];
        }
    }
    double x[6];
    for (int i = 5; i >= 0; --i) {
        double s = A[i][6];
        for (int j = i + 1; j < 6; ++j) s -= A[i][j] * x[j];
        x[i] = s / A[i][i];
    }

    const double rho[3] = { x[0], x[1], x[2] };
    const double phi[3] = { x[3], x[4], x[5] };
    const double th2 = phi[0]*phi[0] + phi[1]*phi[1] + phi[2]*phi[2];
    const bool small = th2 < 1e-8;
    const double th2s = small ? 1.0 : th2;
    const double th = sqrt(th2s);
    const double Ac = small ? 1.0 - th2 / 6.0   : sin(th) / th;
    const double Bc = small ? 0.5 - th2 / 24.0  : (1.0 - cos(th)) / th2s;
    const double Cc = small ? 1.0/6.0 - th2/120.0 : (th - sin(th)) / (th2s * th);
    const double Kh[3][3] = { { 0.0, -phi[2],  phi[1] },
                              {  phi[2], 0.0, -phi[0] },
                              { -phi[1],  phi[0], 0.0 } };
    double K2[3][3];
    for (int i = 0; i < 3; ++i)
        for (int j = 0; j < 3; ++j) {
            double s = 0.0;
            for (int k = 0; k < 3; ++k) s += Kh[i][k] * Kh[k][j];
            K2[i][j] = s;
        }
    double T[4][4];
    for (int i = 0; i < 3; ++i)
        for (int j = 0; j < 3; ++j) {
            double I = (i == j) ? 1.0 : 0.0;
            T[i][j] = I + Ac * Kh[i][j] + Bc * K2[i][j];
        }
    for (int i = 0; i < 3; ++i) {
        double s = 0.0;
        for (int j = 0; j < 3; ++j) {
            double I = (i == j) ? 1.0 : 0.0;
            double V = I + Bc * Kh[i][j] + Cc * K2[i][j];
            s += V * rho[j];
        }
        T[i][3] = s;
    }
    T[3][0] = 0.0; T[3][1] = 0.0; T[3][2] = 0.0; T[3][3] = 1.0;

    const float* pz = poses + b * 16;
    for (int i = 0; i < 4; ++i)
        for (int j = 0; j < 4; ++j) {
            double s = 0.0;
            for (int k = 0; k < 4; ++k) s += T[i][k] * (double)pz[k * 4 + j];
            out[b * 16 + i * 4 + j] = (float)s;
        }
    for (int k = 0; k < 6; ++k)
        out[BATCH * 16 + b * 6 + k] = (float)x[k];
}

extern "C" void kernel_launch(void* const* d_in, const int* in_sizes, int n_in,
                              void* d_out, int out_size, void* d_ws, size_t ws_size,
                              hipStream_t stream) {
    const float* poses    = (const float*)d_in[0];
    const float* calibK   = (const float*)d_in[1];
    const float* p2       = (const float*)d_in[2];
    const float* P2       = (const float*)d_in[3];
    const float* weight   = (const float*)d_in[4];
    const float* src_feat = (const float*)d_in[5];
    const float* tgt_feat = (const float*)d_in[6];
    const float* src_w    = (const float*)d_in[7];
    const float* tgt_w    = (const float*)d_in[8];
    float* out = (float*)d_out;

    char*  tf8      = (char*)d_ws;                             // B*HW*16 bytes (7.9 MB)
    float* partials = (float*)(tf8 + (size_t)BATCH * HW * 16); // B*NSLOT*NPART floats (2 MB)

    hipLaunchKernelGGL(transpose_tgt, dim3(HW / 256, BATCH), dim3(256), 0, stream,
                       tgt_feat, tf8);
    hipLaunchKernelGGL(gn_accum, dim3(NBLK * BATCH), dim3(256), 0, stream,
                       p2, P2, calibK, weight, src_feat, src_w, tgt_w, tf8, partials);
    hipLaunchKernelGGL(gn_solve, dim3(BATCH), dim3(256), 0, stream,
                       partials, poses, out);
}

// Round 6
// 63.242 us; speedup vs baseline: 1.1667x; 1.1667x over previous
//
#include <hip/hip_runtime.h>
#include <math.h>

#define BATCH 16
#define CHN   16
#define IMH   96
#define IMW   320
#define HW    (IMH*IMW)          /* 30720 */
#define NBLK  (HW/256)           /* 120 blocks per batch */
#define NPART 27                 /* 21 (sym H) + 6 (b) */
#define MAPB  (HW*16)            /* fp8 map bytes per batch (row-pair tiled) */

typedef __attribute__((ext_vector_type(2))) float f32x2;

__device__ __forceinline__ int comp4(int4 v, int k) {
    switch (k) { case 0: return v.x; case 1: return v.y; case 2: return v.z; default: return v.w; }
}

// wave64 sum via DPP (row_shr 1/2/4/8 + row_bcast 15/31); result valid in lane 63.
__device__ __forceinline__ float dpp_wave_sum(float x) {
    union fi { float f; int i; };
    fi v; v.f = x;
#define DPPSTEP(CTRL, RM) { fi t; t.i = __builtin_amdgcn_update_dpp(0, v.i, CTRL, RM, 0xf, true); v.f += t.f; }
    DPPSTEP(0x111, 0xf)   /* row_shr:1 */
    DPPSTEP(0x112, 0xf)   /* row_shr:2 */
    DPPSTEP(0x114, 0xf)   /* row_shr:4 */
    DPPSTEP(0x118, 0xf)   /* row_shr:8  -> lane 15+16r = row sum */
    DPPSTEP(0x142, 0xa)   /* row_bcast:15 */
    DPPSTEP(0x143, 0xc)   /* row_bcast:31 -> lane63 = total */
#undef DPPSTEP
    return v.f;
}

// ---- kernel 0: tgt_feat (B,C,H,W) fp32 -> row-pair-tiled fp8 map; tgt_w fp32 -> fp8 map ----
// pixel (x,y) of batch b lives at tf8 + b*MAPB + ((y>>1)*IMW + x)*32 + (y&1)*16
__global__ __launch_bounds__(256) void transpose_tgt(const float* __restrict__ in,
                                                     const float* __restrict__ tw,
                                                     char* __restrict__ out,
                                                     char* __restrict__ tw8) {
    const int b = blockIdx.y;
    const int p = blockIdx.x * 256 + threadIdx.x;
    const int y = p / IMW, x = p - y * IMW;
    const float* ip = in + (size_t)b * CHN * HW + p;
    float f[16];
#pragma unroll
    for (int c = 0; c < 16; ++c) f[c] = ip[c * HW];
    int4 pk;
    int* pw = &pk.x;
#pragma unroll
    for (int k = 0; k < 4; ++k) {
        int dw = __builtin_amdgcn_cvt_pk_fp8_f32(f[4 * k + 0], f[4 * k + 1], 0, false);
        dw     = __builtin_amdgcn_cvt_pk_fp8_f32(f[4 * k + 2], f[4 * k + 3], dw, true);
        pw[k] = dw;
    }
    *(int4*)(out + (size_t)b * MAPB + ((size_t)(y >> 1) * IMW + x) * 32 + (y & 1) * 16) = pk;

    const float wv = tw[(size_t)b * HW + p];
    int wq = __builtin_amdgcn_cvt_pk_fp8_f32(wv, wv, 0, false);
    tw8[(size_t)b * HW + p] = (char)(wq & 0xff);
}

// ---- kernel 1: per-point moments + block-partial H/b (fp8 gathers, row-pair tiled) ----
__global__ __launch_bounds__(256, 4) void gn_accum(
    const float* __restrict__ p2,        // (B,2,5,1,H,W)
    const float* __restrict__ P2,        // (B,3,HW)
    const float* __restrict__ calibK,    // (B,3,3)
    const float* __restrict__ weight,    // (B,1,H,W)
    const float* __restrict__ src_feat,  // (B,C,H,W)
    const float* __restrict__ src_w,     // (B,1,H,W)
    const char* __restrict__ tw8,        // (B,H,W) fp8 tgt_w
    const char* __restrict__ tf8,        // row-pair tiled fp8 tgt_feat
    float* __restrict__ partials)        // (B, NBLK, NPART)
{
    __shared__ float xs_l[1280];
    __shared__ float ys_l[1280];
    __shared__ float red[4][NPART];

    // XCD pinning: XCD k serves batches {k, k+8} -> 2 fp8 maps (~1 MB) per L2
    const int n   = blockIdx.x;
    const int b   = n & 15;
    const int blk = n >> 4;
    const int t   = threadIdx.x;
    const int p   = blk * 256 + t;

    // ---- cooperative coalesced stage of the block's 1280 grid coords ----
    const unsigned Gblk0 = ((unsigned)b * HW + (unsigned)(blk * 256)) * 5u;
#pragma unroll
    for (int j = 0; j < 5; ++j) {
        const unsigned idx  = (unsigned)(j * 256 + t);
        const unsigned G    = Gblk0 + idx;
        const unsigned sBig = G / (unsigned)(BATCH * HW);
        const unsigned r    = G - sBig * (unsigned)(BATCH * HW);
        const unsigned bb   = r / (unsigned)HW;
        const unsigned q    = r - bb * (unsigned)HW;
        const float* pb = p2 + (size_t)bb * (10 * HW) + (size_t)sBig * HW + q;
        xs_l[idx] = pb[0];
        ys_l[idx] = pb[5 * HW];
    }
    __syncthreads();

    // ---- per-point sample geometry from LDS ----
    int   offA[5], offC[5];   // byte offsets of row y0 span and row y0+1 span
    float wxs[5], wys[5];
    int   pixw = 0;           // flat pixel for tgt_w corners (sample 0)
#pragma unroll
    for (int s = 0; s < 5; ++s) {
        const float xp = xs_l[5 * t + s];
        const float yp = ys_l[5 * t + s];
        float gx = 2.0f * (xp + 0.5f) / (float)IMW - 1.0f;
        float gy = 2.0f * (yp + 0.5f) / (float)IMH - 1.0f;
        float x  = (gx + 1.0f) * ((float)IMW * 0.5f) - 0.5f;
        float y  = (gy + 1.0f) * ((float)IMH * 0.5f) - 0.5f;
        float x0 = floorf(x), y0 = floorf(y);
        wxs[s] = x - x0;
        wys[s] = y - y0;
        int xi = (int)x0, yi = (int)y0;
        xi = min(max(xi, 0), IMW - 2);
        yi = min(max(yi, 0), IMH - 2);
        const int h0 = yi >> 1, par0 = yi & 1;
        const int h1 = h0 + par0, par1 = par0 ^ 1;
        offA[s] = (h0 * IMW + xi) * 32 + par0 * 16;
        offC[s] = (h1 * IMW + xi) * 32 + par1 * 16;
        if (s == 0) pixw = yi * IMW + xi;
    }

    // ---- issue loads: 20 fp8 feature gathers + 4 fp8 tgt_w bytes + coalesced streams ----
    const char* mapb = tf8 + (size_t)b * MAPB;
    int4 LA[5], LB[5], LC[5], LD[5];
#pragma unroll
    for (int s = 0; s < 5; ++s) {
        LA[s] = *(const int4*)(mapb + offA[s]);
        LB[s] = *(const int4*)(mapb + offA[s] + 32);
        LC[s] = *(const int4*)(mapb + offC[s]);
        LD[s] = *(const int4*)(mapb + offC[s] + 32);
    }
    const char* twb = tw8 + (size_t)b * HW + pixw;
    const int tb00 = (int)(unsigned char)twb[0];
    const int tb01 = (int)(unsigned char)twb[1];
    const int tb10 = (int)(unsigned char)twb[IMW];
    const int tb11 = (int)(unsigned char)twb[IMW + 1];

    float srcv[16];
    const float* srcb = src_feat + (size_t)b * CHN * HW + p;
#pragma unroll
    for (int c = 0; c < 16; ++c) srcv[c] = srcb[c * HW];

    const float* P2b = P2 + (size_t)b * 3 * HW;
    const float X = P2b[p], Y = P2b[HW + p], Z = P2b[2 * HW + p];
    const float wP  = weight[(size_t)b * HW + p];
    const float swP = src_w[(size_t)b * HW + p];

    // ---- pixel Jacobian rows ----
    const float fx = calibK[b * 9 + 0];
    const float fy = calibK[b * 9 + 4];
    const float fxZ = fx / Z, fyZ = fy / Z;
    const float fxXZ2 = fxZ * X / Z;
    const float fyYZ2 = fyZ * Y / Z;
    float r0[6] = { fxZ, 0.0f, -fxXZ2, -fxXZ2 * Y, fx + fxXZ2 * X, -fxZ * Y };
    float r1[6] = { 0.0f, fyZ, -fyYZ2, -fy - fyYZ2 * Y, fyYZ2 * X, fyZ * X };

    // ---- weights (tgt_w corners decoded from fp8) ----
    float wtw;
    {
        float wx = wxs[0], wy = wys[0];
        float v00 = __builtin_amdgcn_cvt_pk_f32_fp8(tb00, false)[0];
        float v01 = __builtin_amdgcn_cvt_pk_f32_fp8(tb01, false)[0];
        float v10 = __builtin_amdgcn_cvt_pk_f32_fp8(tb10, false)[0];
        float v11 = __builtin_amdgcn_cvt_pk_f32_fp8(tb11, false)[0];
        wtw = v00 * (1.0f - wx) * (1.0f - wy) + v01 * wx * (1.0f - wy)
            + v10 * (1.0f - wx) * wy          + v11 * wx * wy;
    }
    const float w = swP * wtw * wP;

    float w00[5], w01[5], w10[5], w11[5];
#pragma unroll
    for (int s = 0; s < 5; ++s) {
        float wx = wxs[s], wy = wys[s];
        w00[s] = (1.0f - wx) * (1.0f - wy);
        w01[s] = wx * (1.0f - wy);
        w10[s] = (1.0f - wx) * wy;
        w11[s] = wx * wy;
    }

    // ---- channel-dword passes: decode fp8, bilinear-mix, accumulate moments ----
    float Sxx = 0.0f, Sxy = 0.0f, Syy = 0.0f, Tx = 0.0f, Ty = 0.0f;
#pragma unroll
    for (int k = 0; k < 4; ++k) {
        float fs[5][4];
#pragma unroll
        for (int s = 0; s < 5; ++s) {
            f32x2 alo = __builtin_amdgcn_cvt_pk_f32_fp8(comp4(LA[s], k), false);
            f32x2 ahi = __builtin_amdgcn_cvt_pk_f32_fp8(comp4(LA[s], k), true);
            f32x2 blo = __builtin_amdgcn_cvt_pk_f32_fp8(comp4(LB[s], k), false);
            f32x2 bhi = __builtin_amdgcn_cvt_pk_f32_fp8(comp4(LB[s], k), true);
            f32x2 clo = __builtin_amdgcn_cvt_pk_f32_fp8(comp4(LC[s], k), false);
            f32x2 chi = __builtin_amdgcn_cvt_pk_f32_fp8(comp4(LC[s], k), true);
            f32x2 dlo = __builtin_amdgcn_cvt_pk_f32_fp8(comp4(LD[s], k), false);
            f32x2 dhi = __builtin_amdgcn_cvt_pk_f32_fp8(comp4(LD[s], k), true);
            float a[4]  = { alo[0], alo[1], ahi[0], ahi[1] };
            float bq[4] = { blo[0], blo[1], bhi[0], bhi[1] };
            float c[4]  = { clo[0], clo[1], chi[0], chi[1] };
            float d[4]  = { dlo[0], dlo[1], dhi[0], dhi[1] };
#pragma unroll
            for (int j = 0; j < 4; ++j)
                fs[s][j] = a[j] * w00[s] + bq[j] * w01[s] + c[j] * w10[s] + d[j] * w11[s];
        }
#pragma unroll
        for (int j = 0; j < 4; ++j) {
            float sv  = srcv[4 * k + j];
            float res = sv - fs[0][j];
            float gx  = (fs[1][j] - fs[2][j]) * 0.5f;
            float gy  = (fs[3][j] - fs[4][j]) * 0.5f;
            Sxx += gx * gx; Sxy += gx * gy; Syy += gy * gy;
            Tx  += res * gx; Ty  += res * gy;
        }
    }

    const float Pm = w * Sxx, Qm = w * Sxy, Rm = w * Syy;
    const float tx = w * Tx,  ty = w * Ty;

    // ---- 27 values: DPP wave sum (lane 63) -> LDS -> block combine ----
    const int wv   = t >> 6;
    const int lane = t & 63;

    int idx = 0;
#pragma unroll
    for (int k = 0; k < 6; ++k) {
#pragma unroll
        for (int l = 0; l < 6; ++l) {
            if (l < k) continue;
            float v = Pm * r0[k] * r0[l]
                    + Qm * (r0[k] * r1[l] + r1[k] * r0[l])
                    + Rm * r1[k] * r1[l];
            v = dpp_wave_sum(v);
            if (lane == 63) red[wv][idx] = v;
            ++idx;
        }
    }
#pragma unroll
    for (int k = 0; k < 6; ++k) {
        float v = tx * r0[k] + ty * r1[k];
        v = dpp_wave_sum(v);
        if (lane == 63) red[wv][21 + k] = v;
    }
    __syncthreads();
    if (t < NPART) {
        float s = red[0][t] + red[1][t] + red[2][t] + red[3][t];
        partials[((size_t)b * NBLK + blk) * NPART + t] = s;
    }
}

// ---------------- kernel 2: double reduce + solve + se3_exp + compose ----------------
__global__ __launch_bounds__(256) void gn_solve(
    const float* __restrict__ partials,
    const float* __restrict__ poses,
    float* __restrict__ out)
{
    const int b = blockIdx.x;
    const int t = threadIdx.x;
    __shared__ double dsum[8][NPART];
    __shared__ double sums[NPART];

    if (t < 216) {
        const int col = t % NPART;
        const int g   = t / NPART;     // 0..7
        double s = 0.0;
        for (int j = g; j < NBLK; j += 8)
            s += (double)partials[((size_t)b * NBLK + j) * NPART + col];
        dsum[g][col] = s;
    }
    __syncthreads();
    if (t < NPART) {
        double s = 0.0;
#pragma unroll
        for (int g = 0; g < 8; ++g) s += dsum[g][t];
        sums[t] = s;
    }
    __syncthreads();
    if (t != 0) return;

    double A[6][7];
    {
        int idx = 0;
        for (int k = 0; k < 6; ++k)
            for (int l = k; l < 6; ++l) {
                A[k][l] = sums[idx];
                A[l][k] = sums[idx];
                ++idx;
            }
        for (int k = 0; k < 6; ++k) A[k][6] = sums[21 + k];
    }
    for (int col = 0; col < 6; ++col) {
        int piv = col; double mx = fabs(A[col][col]);
        for (int rr = col + 1; rr < 6; ++rr) {
            double v = fabs(A[rr][col]);
            if (v > mx) { mx = v; piv = rr; }
        }
        if (piv != col)
            for (int j = col; j < 7; ++j) { double tmp = A[col][j]; A[col][j] = A[piv][j]; A[piv][j] = tmp; }
        double d = A[col][col];
        for (int rr = col + 1; rr < 6; ++rr) {
            double f = A[rr][col] / d;
            for (int j = col; j < 7; ++j) A[rr][j] -= f * A[col][j];
        }
    }
    double x[6];
    for (int i = 5; i >= 0; --i) {
        double s = A[i][6];
        for (int j = i + 1; j < 6; ++j) s -= A[i][j] * x[j];
        x[i] = s / A[i][i];
    }

    const double rho[3] = { x[0], x[1], x[2] };
    const double phi[3] = { x[3], x[4], x[5] };
    const double th2 = phi[0]*phi[0] + phi[1]*phi[1] + phi[2]*phi[2];
    const bool small = th2 < 1e-8;
    const double th2s = small ? 1.0 : th2;
    const double th = sqrt(th2s);
    const double Ac = small ? 1.0 - th2 / 6.0   : sin(th) / th;
    const double Bc = small ? 0.5 - th2 / 24.0  : (1.0 - cos(th)) / th2s;
    const double Cc = small ? 1.0/6.0 - th2/120.0 : (th - sin(th)) / (th2s * th);
    const double Kh[3][3] = { { 0.0, -phi[2],  phi[1] },
                              {  phi[2], 0.0, -phi[0] },
                              { -phi[1],  phi[0], 0.0 } };
    double K2[3][3];
    for (int i = 0; i < 3; ++i)
        for (int j = 0; j < 3; ++j) {
            double s = 0.0;
            for (int k = 0; k < 3; ++k) s += Kh[i][k] * Kh[k][j];
            K2[i][j] = s;
        }
    double T[4][4];
    for (int i = 0; i < 3; ++i)
        for (int j = 0; j < 3; ++j) {
            double I = (i == j) ? 1.0 : 0.0;
            T[i][j] = I + Ac * Kh[i][j] + Bc * K2[i][j];
        }
    for (int i = 0; i < 3; ++i) {
        double s = 0.0;
        for (int j = 0; j < 3; ++j) {
            double I = (i == j) ? 1.0 : 0.0;
            double V = I + Bc * Kh[i][j] + Cc * K2[i][j];
            s += V * rho[j];
        }
        T[i][3] = s;
    }
    T[3][0] = 0.0; T[3][1] = 0.0; T[3][2] = 0.0; T[3][3] = 1.0;

    const float* pz = poses + b * 16;
    for (int i = 0; i < 4; ++i)
        for (int j = 0; j < 4; ++j) {
            double s = 0.0;
            for (int k = 0; k < 4; ++k) s += T[i][k] * (double)pz[k * 4 + j];
            out[b * 16 + i * 4 + j] = (float)s;
        }
    for (int k = 0; k < 6; ++k)
        out[BATCH * 16 + b * 6 + k] = (float)x[k];
}

extern "C" void kernel_launch(void* const* d_in, const int* in_sizes, int n_in,
                              void* d_out, int out_size, void* d_ws, size_t ws_size,
                              hipStream_t stream) {
    const float* poses    = (const float*)d_in[0];
    const float* calibK   = (const float*)d_in[1];
    const float* p2       = (const float*)d_in[2];
    const float* P2       = (const float*)d_in[3];
    const float* weight   = (const float*)d_in[4];
    const float* src_feat = (const float*)d_in[5];
    const float* tgt_feat = (const float*)d_in[6];
    const float* src_w    = (const float*)d_in[7];
    const float* tgt_w    = (const float*)d_in[8];
    float* out = (float*)d_out;

    char*  tf8      = (char*)d_ws;                              // B*MAPB bytes (7.9 MB)
    char*  tw8      = tf8 + (size_t)BATCH * MAPB;               // B*HW bytes (0.5 MB)
    float* partials = (float*)(tw8 + (size_t)BATCH * HW);       // B*NBLK*NPART floats

    hipLaunchKernelGGL(transpose_tgt, dim3(HW / 256, BATCH), dim3(256), 0, stream,
                       tgt_feat, tgt_w, tf8, tw8);
    hipLaunchKernelGGL(gn_accum, dim3(NBLK * BATCH), dim3(256), 0, stream,
                       p2, P2, calibK, weight, src_feat, src_w, tw8, tf8, partials);
    hipLaunchKernelGGL(gn_solve, dim3(BATCH), dim3(256), 0, stream,
                       partials, poses, out);
}